// Round 1
// baseline (1753.669 us; speedup 1.0000x reference)
//
#include <hip/hip_runtime.h>

#define CI 2048
#define CO_N 2048
#define SLOT 64
#define SPC 4
#define NELEM (CI*SPC*SLOT)          // 524288
#define CAP 256                      // SPC*SLOT per capsule
#define WI_PER_CAP 65536             // SLOT*SLOT*SPC*SPC

__device__ __forceinline__ float gelu_tanh(float x) {
    const float c0 = 0.7978845608028654f; // sqrt(2/pi)
    float x3 = x * x * x;
    float t = tanhf(c0 * (x + 0.044715f * x3));
    return 0.5f * x * (1.0f + t);
}

// K1: per-capsule matmul + gelu, per-block sum/sumsq partials.
// y[i,l,j] = sum_{k,m} Wi[i,j,k,l,m] * x[i,m,k]
__global__ __launch_bounds__(256) void k1_capsule_mm(
    const float* __restrict__ x, const float* __restrict__ Wi,
    float* __restrict__ y, float* __restrict__ psum, float* __restrict__ psumsq)
{
    __shared__ float xs[CAP];
    __shared__ float ys[CAP];
    __shared__ float ws_s[4], ws_q[4];
    const int i = blockIdx.x;
    const int t = threadIdx.x;
    xs[t] = x[(size_t)i * CAP + t];
    __syncthreads();

    const int j = t >> 2;   // slot (0..63)
    const int l = t & 3;    // spc  (0..3)
    // float offset: i*65536 + j*1024 + k*16 + l*4 + m ; read (l fixed, m=0..3) as float4
    const float4* W4 = (const float4*)(Wi + (size_t)i * WI_PER_CAP + j * 1024 + l * 4);
    float acc = 0.f;
    #pragma unroll 8
    for (int k = 0; k < 64; ++k) {
        float4 w = W4[k * 4];
        acc += w.x * xs[k] + w.y * xs[64 + k] + w.z * xs[128 + k] + w.w * xs[192 + k];
    }
    float g = gelu_tanh(acc);
    ys[l * 64 + j] = g;       // transpose for coalesced store

    // block reduction of g, g^2
    float s = g, q = g * g;
    #pragma unroll
    for (int off = 32; off > 0; off >>= 1) {
        s += __shfl_down(s, off);
        q += __shfl_down(q, off);
    }
    const int wid = t >> 6, lane = t & 63;
    if (lane == 0) { ws_s[wid] = s; ws_q[wid] = q; }
    __syncthreads();
    y[(size_t)i * CAP + t] = ys[t];
    if (t == 0) {
        psum[i]   = ws_s[0] + ws_s[1] + ws_s[2] + ws_s[3];
        psumsq[i] = ws_q[0] + ws_q[1] + ws_q[2] + ws_q[3];
    }
}

// K2: final stats reduction -> stats[0]=mu, stats[1]=rsqrt(var+eps)
__global__ __launch_bounds__(256) void k2_stats(
    const float* __restrict__ psum, const float* __restrict__ psumsq,
    float* __restrict__ stats)
{
    __shared__ float as[4], aq[4];
    const int t = threadIdx.x;
    float s = 0.f, q = 0.f;
    for (int b = t; b < CI; b += 256) { s += psum[b]; q += psumsq[b]; }
    #pragma unroll
    for (int off = 32; off > 0; off >>= 1) {
        s += __shfl_down(s, off);
        q += __shfl_down(q, off);
    }
    if ((t & 63) == 0) { as[t >> 6] = s; aq[t >> 6] = q; }
    __syncthreads();
    if (t == 0) {
        float S = as[0] + as[1] + as[2] + as[3];
        float Q = aq[0] + aq[1] + aq[2] + aq[3];
        float mu = S / (float)NELEM;
        float var = Q / (float)NELEM - mu * mu;
        stats[0] = mu;
        stats[1] = rsqrtf(var + 1e-6f);
    }
}

// K3: in-place global layernorm apply
__global__ __launch_bounds__(256) void k3_norm(
    float* __restrict__ y, const float* __restrict__ scale,
    const float* __restrict__ bias, const float* __restrict__ stats)
{
    const int idx = blockIdx.x * 256 + threadIdx.x;
    const float mu = stats[0], inv = stats[1];
    y[idx] = (y[idx] - mu) * inv * scale[idx] + bias[idx];
}

// K4: routing. out[k,l,m] = sum_{i,j} Co[i,j,k,l] * yn[i,j,m]
// one wave per k (4 k per block); lane: l = lane>>4, m4 = lane&15 (float4 of m)
__global__ __launch_bounds__(256) void k4_route(
    const float* __restrict__ Co, const float* __restrict__ yn,
    float* __restrict__ out)
{
    const int t = threadIdx.x;
    const int k = blockIdx.x * 4 + (t >> 6);
    const int lane = t & 63;
    const int l = lane >> 4;
    const int m4 = lane & 15;
    const float* cop = Co + (size_t)k * 4 + l;       // + ij*8192
    const float4* y4 = (const float4*)yn + m4;       // + ij*16
    float4 acc = {0.f, 0.f, 0.f, 0.f};
    #pragma unroll 4
    for (int ij = 0; ij < CI * SPC; ++ij) {
        float c  = cop[(size_t)ij * 8192];
        float4 v = y4[(size_t)ij * 16];
        acc.x += c * v.x;
        acc.y += c * v.y;
        acc.z += c * v.z;
        acc.w += c * v.w;
    }
    float4* o4 = (float4*)(out + (size_t)k * CAP + l * 64 + m4 * 4);
    *o4 = acc;
}

extern "C" void kernel_launch(void* const* d_in, const int* in_sizes, int n_in,
                              void* d_out, int out_size, void* d_ws, size_t ws_size,
                              hipStream_t stream) {
    const float* x        = (const float*)d_in[0];
    const float* Wi       = (const float*)d_in[1];
    const float* ln_scale = (const float*)d_in[2];
    const float* ln_bias  = (const float*)d_in[3];
    const float* Co       = (const float*)d_in[4];
    float* out = (float*)d_out;

    // workspace layout
    float* y      = (float*)d_ws;                 // 524288 floats (2 MB)
    float* psum   = y + NELEM;                    // 2048 floats
    float* psumsq = psum + CI;                    // 2048 floats
    float* stats  = psumsq + CI;                  // 2 floats

    k1_capsule_mm<<<CI, 256, 0, stream>>>(x, Wi, y, psum, psumsq);
    k2_stats<<<1, 256, 0, stream>>>(psum, psumsq, stats);
    k3_norm<<<NELEM / 256, 256, 0, stream>>>(y, ln_scale, ln_bias, stats);
    k4_route<<<CO_N / 4, 256, 0, stream>>>(Co, y, out);
}

// Round 2
// 1341.511 us; speedup vs baseline: 1.3072x; 1.3072x over previous
//
#include <hip/hip_runtime.h>

#define CI 2048
#define CO_N 2048
#define SLOT 64
#define SPC 4
#define NELEM (CI*SPC*SLOT)          // 524288
#define CAP 256                      // SPC*SLOT per capsule
#define IJ (CI*SPC)                  // 8192
#define P_SPLIT 16                   // ij partitions in k4
#define IJ_CHUNK (IJ/P_SPLIT)        // 512

__device__ __forceinline__ float gelu_tanh(float x) {
    const float c0 = 0.7978845608028654f; // sqrt(2/pi)
    float x3 = x * x * x;
    float t = tanhf(c0 * (x + 0.044715f * x3));
    return 0.5f * x * (1.0f + t);
}

// K1: y[i,l,j] = sum_{k,m} Wi[i,j,k,l,m] * x[i,m,k]
// thread t = (k = t>>2, l = t&3); loop over j: wave reads 1KB CONTIGUOUS float4s.
// k-reduction: 4x shfl_xor butterfly (16 lanes share l) + cross-wave LDS combine.
__global__ __launch_bounds__(256) void k1_capsule_mm(
    const float* __restrict__ x, const float* __restrict__ Wi,
    float* __restrict__ y, float* __restrict__ psum, float* __restrict__ psumsq)
{
    __shared__ float xs[CAP];
    __shared__ float part[4][4][SLOT];   // [wave][l][j]
    __shared__ float ws_s[4], ws_q[4];
    const int i = blockIdx.x;
    const int t = threadIdx.x;
    xs[t] = x[(size_t)i * CAP + t];
    __syncthreads();

    const int k = t >> 2;
    const int w = t >> 6;
    const float xk0 = xs[k], xk1 = xs[64 + k], xk2 = xs[128 + k], xk3 = xs[192 + k];
    const float4* W4 = (const float4*)Wi + (size_t)i * 16384 + t;  // +j*256 per j

    #pragma unroll 8
    for (int j = 0; j < SLOT; ++j) {
        float4 wv = W4[(size_t)j * 256];
        float p = wv.x * xk0 + wv.y * xk1 + wv.z * xk2 + wv.w * xk3;
        p += __shfl_xor(p, 4);
        p += __shfl_xor(p, 8);
        p += __shfl_xor(p, 16);
        p += __shfl_xor(p, 32);
        if ((t & 63) < 4) part[w][t & 63][j] = p;   // lanes 0..3 hold l=0..3
    }
    __syncthreads();

    // epilogue: thread t -> (l2 = t>>6, j2 = t&63), coalesced y store
    const int l2 = t >> 6, j2 = t & 63;
    float v = part[0][l2][j2] + part[1][l2][j2] + part[2][l2][j2] + part[3][l2][j2];
    float g = gelu_tanh(v);
    y[(size_t)i * CAP + t] = g;

    float s = g, q = g * g;
    #pragma unroll
    for (int off = 32; off > 0; off >>= 1) {
        s += __shfl_down(s, off);
        q += __shfl_down(q, off);
    }
    if ((t & 63) == 0) { ws_s[w] = s; ws_q[w] = q; }
    __syncthreads();
    if (t == 0) {
        psum[i]   = ws_s[0] + ws_s[1] + ws_s[2] + ws_s[3];
        psumsq[i] = ws_q[0] + ws_q[1] + ws_q[2] + ws_q[3];
    }
}

// K2: final stats reduction -> stats[0]=mu, stats[1]=rsqrt(var+eps)
__global__ __launch_bounds__(256) void k2_stats(
    const float* __restrict__ psum, const float* __restrict__ psumsq,
    float* __restrict__ stats)
{
    __shared__ float as[4], aq[4];
    const int t = threadIdx.x;
    float s = 0.f, q = 0.f;
    for (int b = t; b < CI; b += 256) { s += psum[b]; q += psumsq[b]; }
    #pragma unroll
    for (int off = 32; off > 0; off >>= 1) {
        s += __shfl_down(s, off);
        q += __shfl_down(q, off);
    }
    if ((t & 63) == 0) { as[t >> 6] = s; aq[t >> 6] = q; }
    __syncthreads();
    if (t == 0) {
        float S = as[0] + as[1] + as[2] + as[3];
        float Q = aq[0] + aq[1] + aq[2] + aq[3];
        float mu = S / (float)NELEM;
        float var = Q / (float)NELEM - mu * mu;
        stats[0] = mu;
        stats[1] = rsqrtf(var + 1e-6f);
    }
}

// K3: in-place global layernorm apply
__global__ __launch_bounds__(256) void k3_norm(
    float* __restrict__ y, const float* __restrict__ scale,
    const float* __restrict__ bias, const float* __restrict__ stats)
{
    const int idx = blockIdx.x * 256 + threadIdx.x;
    const float mu = stats[0], inv = stats[1];
    y[idx] = (y[idx] - mu) * inv * scale[idx] + bias[idx];
}

// K4: out[k,l,m] = sum_ij Co[ij,k,l] * yn[ij,m]
// block = (kb: 64 k's) x (pc: 512-ij chunk); thread t = (k_t = t>>2, l = t&3)
// acc[64] (m) in VGPRs; Co read coalesced (block slice = 256 contiguous floats/ij);
// yn staged in double-buffered LDS (8 ij per group), broadcast reads.
// fp32 atomicAdd epilogue into out (out zeroed via memset before launch).
__global__ __launch_bounds__(256) void k4_route(
    const float* __restrict__ Co, const float* __restrict__ yn,
    float* __restrict__ out)
{
    __shared__ float ys[2][8 * 64];   // 2 x 2KB
    const int t  = threadIdx.x;
    const int kb = blockIdx.x;        // 0..31
    const int pc = blockIdx.y;        // 0..P_SPLIT-1
    const int ij0 = pc * IJ_CHUNK;

    float4 acc[16];
    #pragma unroll
    for (int u = 0; u < 16; ++u) acc[u] = make_float4(0.f, 0.f, 0.f, 0.f);

    const float*  cop = Co + (size_t)ij0 * 8192 + kb * 256 + t;
    const float2* yp  = (const float2*)(yn + (size_t)ij0 * 64) + t;

    for (int g = 0; g < IJ_CHUNK / 8; ++g) {
        const int buf = g & 1;
        // issue independent global loads before the barrier
        float2 yv = yp[(size_t)g * 256];
        float cc[8];
        #pragma unroll
        for (int u = 0; u < 8; ++u) cc[u] = cop[(size_t)(g * 8 + u) * 8192];
        ((float2*)ys[buf])[t] = yv;
        __syncthreads();
        #pragma unroll
        for (int u = 0; u < 8; ++u) {
            const float c = cc[u];
            const float4* yq = (const float4*)(ys[buf] + u * 64);
            #pragma unroll
            for (int m4 = 0; m4 < 16; ++m4) {
                float4 vv = yq[m4];
                acc[m4].x += c * vv.x;
                acc[m4].y += c * vv.y;
                acc[m4].z += c * vv.z;
                acc[m4].w += c * vv.w;
            }
        }
    }

    float* op = out + (size_t)(kb * 64 + (t >> 2)) * 256 + (t & 3) * 64;
    #pragma unroll
    for (int m4 = 0; m4 < 16; ++m4) {
        atomicAdd(op + m4 * 4 + 0, acc[m4].x);
        atomicAdd(op + m4 * 4 + 1, acc[m4].y);
        atomicAdd(op + m4 * 4 + 2, acc[m4].z);
        atomicAdd(op + m4 * 4 + 3, acc[m4].w);
    }
}

extern "C" void kernel_launch(void* const* d_in, const int* in_sizes, int n_in,
                              void* d_out, int out_size, void* d_ws, size_t ws_size,
                              hipStream_t stream) {
    const float* x        = (const float*)d_in[0];
    const float* Wi       = (const float*)d_in[1];
    const float* ln_scale = (const float*)d_in[2];
    const float* ln_bias  = (const float*)d_in[3];
    const float* Co       = (const float*)d_in[4];
    float* out = (float*)d_out;

    float* y      = (float*)d_ws;                 // 524288 floats (2 MB)
    float* psum   = y + NELEM;                    // 2048 floats
    float* psumsq = psum + CI;                    // 2048 floats
    float* stats  = psumsq + CI;                  // 2 floats

    hipMemsetAsync(out, 0, (size_t)out_size * sizeof(float), stream);
    k1_capsule_mm<<<CI, 256, 0, stream>>>(x, Wi, y, psum, psumsq);
    k2_stats<<<1, 256, 0, stream>>>(psum, psumsq, stats);
    k3_norm<<<NELEM / 256, 256, 0, stream>>>(y, ln_scale, ln_bias, stats);
    k4_route<<<dim3(32, P_SPLIT), 256, 0, stream>>>(Co, y, out);
}

// Round 3
// 878.939 us; speedup vs baseline: 1.9952x; 1.5263x over previous
//
#include <hip/hip_runtime.h>
#include <hip/hip_bf16.h>

#define CI 2048
#define CO_N 2048
#define SLOT 64
#define SPC 4
#define NELEM (CI*SPC*SLOT)          // 524288
#define CAP 256                      // SPC*SLOT per capsule
#define IJ (CI*SPC)                  // 8192
#define S_SPLIT 8                    // ij partitions in k4
#define NC 32                        // 32-ij chunks per k4 block (1024/32)

typedef __attribute__((ext_vector_type(8))) short short8;
typedef __attribute__((ext_vector_type(4))) short short4v;
typedef __attribute__((ext_vector_type(4))) float float4v;

union ABFrag { short4v h[2]; short8 v; };

__device__ __forceinline__ unsigned short f2bf(float f) {
    __hip_bfloat16 h = __float2bfloat16(f);   // RNE
    return __builtin_bit_cast(unsigned short, h);
}

__device__ __forceinline__ float gelu_tanh(float x) {
    const float c0 = 0.7978845608028654f; // sqrt(2/pi)
    float x3 = x * x * x;
    float t = tanhf(c0 * (x + 0.044715f * x3));
    return 0.5f * x * (1.0f + t);
}

// K1: y[i,l,j] = sum_{k,m} Wi[i,j,k,l,m] * x[i,m,k]  (unchanged from R2)
__global__ __launch_bounds__(256) void k1_capsule_mm(
    const float* __restrict__ x, const float* __restrict__ Wi,
    float* __restrict__ y, float* __restrict__ psum, float* __restrict__ psumsq)
{
    __shared__ float xs[CAP];
    __shared__ float part[4][4][SLOT];
    __shared__ float ws_s[4], ws_q[4];
    const int i = blockIdx.x;
    const int t = threadIdx.x;
    xs[t] = x[(size_t)i * CAP + t];
    __syncthreads();

    const int k = t >> 2;
    const int w = t >> 6;
    const float xk0 = xs[k], xk1 = xs[64 + k], xk2 = xs[128 + k], xk3 = xs[192 + k];
    const float4* W4 = (const float4*)Wi + (size_t)i * 16384 + t;

    #pragma unroll 8
    for (int j = 0; j < SLOT; ++j) {
        float4 wv = W4[(size_t)j * 256];
        float p = wv.x * xk0 + wv.y * xk1 + wv.z * xk2 + wv.w * xk3;
        p += __shfl_xor(p, 4);
        p += __shfl_xor(p, 8);
        p += __shfl_xor(p, 16);
        p += __shfl_xor(p, 32);
        if ((t & 63) < 4) part[w][t & 63][j] = p;
    }
    __syncthreads();

    const int l2 = t >> 6, j2 = t & 63;
    float v = part[0][l2][j2] + part[1][l2][j2] + part[2][l2][j2] + part[3][l2][j2];
    float g = gelu_tanh(v);
    y[(size_t)i * CAP + t] = g;

    float s = g, q = g * g;
    #pragma unroll
    for (int off = 32; off > 0; off >>= 1) {
        s += __shfl_down(s, off);
        q += __shfl_down(q, off);
    }
    if ((t & 63) == 0) { ws_s[w] = s; ws_q[w] = q; }
    __syncthreads();
    if (t == 0) {
        psum[i]   = ws_s[0] + ws_s[1] + ws_s[2] + ws_s[3];
        psumsq[i] = ws_q[0] + ws_q[1] + ws_q[2] + ws_q[3];
    }
}

// K2: stats[0]=mu, stats[1]=rsqrt(var+eps)
__global__ __launch_bounds__(256) void k2_stats(
    const float* __restrict__ psum, const float* __restrict__ psumsq,
    float* __restrict__ stats)
{
    __shared__ float as[4], aq[4];
    const int t = threadIdx.x;
    float s = 0.f, q = 0.f;
    for (int b = t; b < CI; b += 256) { s += psum[b]; q += psumsq[b]; }
    #pragma unroll
    for (int off = 32; off > 0; off >>= 1) {
        s += __shfl_down(s, off);
        q += __shfl_down(q, off);
    }
    if ((t & 63) == 0) { as[t >> 6] = s; aq[t >> 6] = q; }
    __syncthreads();
    if (t == 0) {
        float S = as[0] + as[1] + as[2] + as[3];
        float Q = aq[0] + aq[1] + aq[2] + aq[3];
        float mu = S / (float)NELEM;
        float var = Q / (float)NELEM - mu * mu;
        stats[0] = mu;
        stats[1] = rsqrtf(var + 1e-6f);
    }
}

// K3: LayerNorm apply + bf16 convert + transpose to ynT[m][ij] (m-major, 8192 ij per row)
// block c = 32-ij chunk; thread t handles 8 m-consecutive elements of one ij.
__global__ __launch_bounds__(256) void k3_norm_t(
    const float* __restrict__ y, const float* __restrict__ scale,
    const float* __restrict__ bias, const float* __restrict__ stats,
    unsigned short* __restrict__ ynT)
{
    const int c = blockIdx.x;        // 0..255
    const int t = threadIdx.x;
    const float mu = stats[0], inv = stats[1];
    const int base = c * 2048 + t * 8;
    float4 ya = *(const float4*)(y + base);
    float4 yb = *(const float4*)(y + base + 4);
    float4 sa = *(const float4*)(scale + base);
    float4 sb = *(const float4*)(scale + base + 4);
    float4 ba = *(const float4*)(bias + base);
    float4 bb = *(const float4*)(bias + base + 4);
    const int ij = c * 32 + (t >> 3);
    const int m0 = (t & 7) * 8;
    float v[8] = { (ya.x-mu)*inv*sa.x+ba.x, (ya.y-mu)*inv*sa.y+ba.y,
                   (ya.z-mu)*inv*sa.z+ba.z, (ya.w-mu)*inv*sa.w+ba.w,
                   (yb.x-mu)*inv*sb.x+bb.x, (yb.y-mu)*inv*sb.y+bb.y,
                   (yb.z-mu)*inv*sb.z+bb.z, (yb.w-mu)*inv*sb.w+bb.w };
    #pragma unroll
    for (int e = 0; e < 8; ++e)
        ynT[(size_t)(m0 + e) * IJ + ij] = f2bf(v[e]);
}

// K4: out[kl,m] = sum_ij Co[ij,kl] * yn[ij,m] via mfma_f32_16x16x32_bf16
// A = Co^T (kl x ij), transposed+bf16 through LDS (stride-72B rows);
// B = yn, read directly from precomputed global ynT[m][ij] (bf16, L2-resident).
// grid (128 kl-blocks of 64, 8 ij-partitions); 4 waves, wave w owns kl [w*16,w*16+16) x all 64 m.
__global__ __launch_bounds__(256) void k4_route_mfma(
    const float* __restrict__ Co, const unsigned short* __restrict__ ynT,
    float* __restrict__ out, float* __restrict__ partial, int use_partial)
{
    __shared__ unsigned short lds_a[64 * 36];   // 64 kl rows x 32 ij (+4 pad) = 72 B rows
    const int t    = threadIdx.x;
    const int kb   = blockIdx.x;        // 0..127
    const int pc   = blockIdx.y;        // 0..7
    const int klb  = kb * 64;
    const int w    = t >> 6;
    const int lane = t & 63;
    const int quad = lane >> 4;
    const int n16  = lane & 15;

    const int p  = t >> 4;              // 0..15: ij pair (2p, 2p+1)
    const int c4 = (t & 15) * 4;        // kl column group

    const float* co_base = Co + ((size_t)(pc * 1024 + 2 * p)) * IJ + klb + c4;
    const unsigned short* ynT_base = ynT + (size_t)(pc * 1024) + quad * 8;

    float4v acc[4];
    #pragma unroll
    for (int mt = 0; mt < 4; ++mt) acc[mt] = (float4v)(0.f);

    float4 co0 = *(const float4*)(co_base);
    float4 co1 = *(const float4*)(co_base + IJ);

    for (int g = 0; g < NC; ++g) {
        __syncthreads();   // previous chunk's readers done
        unsigned int* lw = (unsigned int*)lds_a;
        lw[(c4 + 0) * 18 + p] = (unsigned int)f2bf(co0.x) | ((unsigned int)f2bf(co1.x) << 16);
        lw[(c4 + 1) * 18 + p] = (unsigned int)f2bf(co0.y) | ((unsigned int)f2bf(co1.y) << 16);
        lw[(c4 + 2) * 18 + p] = (unsigned int)f2bf(co0.z) | ((unsigned int)f2bf(co1.z) << 16);
        lw[(c4 + 3) * 18 + p] = (unsigned int)f2bf(co0.w) | ((unsigned int)f2bf(co1.w) << 16);
        __syncthreads();
        if (g + 1 < NC) {   // prefetch next chunk while computing this one
            const float* nb = co_base + (size_t)(g + 1) * 32 * IJ;
            co0 = *(const float4*)(nb);
            co1 = *(const float4*)(nb + IJ);
        }
        // A fragment: kl = klb + w*16 + n16, ij = chunk + quad*8 .. +8
        const unsigned short* arow = lds_a + (w * 16 + n16) * 36 + quad * 8;
        ABFrag af;
        af.h[0] = *(const short4v*)(arow);
        af.h[1] = *(const short4v*)(arow + 4);
        // B fragments from global ynT + 4 mfma
        const unsigned short* yb = ynT_base + (size_t)g * 32;
        #pragma unroll
        for (int mt = 0; mt < 4; ++mt) {
            short8 bf = *(const short8*)(yb + (size_t)(mt * 16 + n16) * IJ);
            acc[mt] = __builtin_amdgcn_mfma_f32_16x16x32_bf16(af.v, bf, acc[mt], 0, 0, 0);
        }
    }

    // D layout: row(kl) = quad*4 + reg, col(m) = n16
    if (use_partial) {
        float* pp = partial + (size_t)pc * NELEM;
        #pragma unroll
        for (int mt = 0; mt < 4; ++mt)
            #pragma unroll
            for (int r = 0; r < 4; ++r)
                pp[(size_t)(klb + w * 16 + quad * 4 + r) * 64 + mt * 16 + n16] = acc[mt][r];
    } else {
        #pragma unroll
        for (int mt = 0; mt < 4; ++mt)
            #pragma unroll
            for (int r = 0; r < 4; ++r)
                atomicAdd(out + (size_t)(klb + w * 16 + quad * 4 + r) * 64 + mt * 16 + n16, acc[mt][r]);
    }
}

// K5: reduce 8 partials -> out (partial path only)
__global__ __launch_bounds__(256) void k5_reduce(
    const float* __restrict__ partial, float* __restrict__ out)
{
    const int idx = blockIdx.x * 256 + threadIdx.x;
    float s = 0.f;
    #pragma unroll
    for (int pcs = 0; pcs < S_SPLIT; ++pcs) s += partial[(size_t)pcs * NELEM + idx];
    out[idx] = s;
}

extern "C" void kernel_launch(void* const* d_in, const int* in_sizes, int n_in,
                              void* d_out, int out_size, void* d_ws, size_t ws_size,
                              hipStream_t stream) {
    const float* x        = (const float*)d_in[0];
    const float* Wi       = (const float*)d_in[1];
    const float* ln_scale = (const float*)d_in[2];
    const float* ln_bias  = (const float*)d_in[3];
    const float* Co       = (const float*)d_in[4];
    float* out = (float*)d_out;

    float* ws = (float*)d_ws;
    float* y      = ws;                       // 524288 floats
    float* psum   = y + NELEM;                // 2048
    float* psumsq = psum + CI;                // 2048
    float* stats  = psumsq + CI;              // 2
    unsigned short* ynT = (unsigned short*)(ws + 528392);   // 524288 ushorts (16B-aligned)
    float* partial = ws + 790536;             // 8 * 524288 floats (partial path)

    const int use_partial = (ws_size >= (size_t)(790536 + S_SPLIT * NELEM) * sizeof(float)) ? 1 : 0;

    k1_capsule_mm<<<CI, 256, 0, stream>>>(x, Wi, y, psum, psumsq);
    k2_stats<<<1, 256, 0, stream>>>(psum, psumsq, stats);
    k3_norm_t<<<256, 256, 0, stream>>>(y, ln_scale, ln_bias, stats, ynT);
    if (!use_partial)
        hipMemsetAsync(out, 0, (size_t)out_size * sizeof(float), stream);
    k4_route_mfma<<<dim3(128, S_SPLIT), 256, 0, stream>>>(Co, ynT, out, partial, use_partial);
    if (use_partial)
        k5_reduce<<<NELEM / 256, 256, 0, stream>>>(partial, out);
}